// Round 2
// baseline (254.468 us; speedup 1.0000x reference)
//
#include <hip/hip_runtime.h>

// Fused attention: B=8, S=2048, D=512, fp32 in/out, bf16 MFMA compute.
// Pipeline: cvt(fp32->bf16) -> qkv_gemm (z=0/1/2 -> Q,K,Vt) -> flash attn
// (split-K flash-decode, counted-vmcnt pipelined) -> combine (split tiles).
// Vt is stored [B][D][S] so PV B-fragments are contiguous ds_read_b128.

typedef unsigned short u16;
typedef unsigned int u32;
typedef u16 u16x4 __attribute__((ext_vector_type(4)));
typedef float f32x4 __attribute__((ext_vector_type(4)));
typedef __bf16 bf16x8 __attribute__((ext_vector_type(8)));

#define NBATCH 8
#define NS 2048
#define ND 512
#define NM (NBATCH*NS)  // 16384 tokens

typedef __attribute__((address_space(1))) u32 gu32;
typedef __attribute__((address_space(3))) u32 lu32;
#define GLD16(g, l) __builtin_amdgcn_global_load_lds((gu32*)(g), (lu32*)(l), 16, 0, 0)

__device__ __forceinline__ u16 f2bf(float f) {  // RNE fp32->bf16
  union { float f; u32 u; } v; v.f = f;
  u32 r = v.u + 0x7FFFu + ((v.u >> 16) & 1u);
  return (u16)(r >> 16);
}

__device__ __forceinline__ f32x4 mfma16(bf16x8 a, bf16x8 b, f32x4 c) {
  return __builtin_amdgcn_mfma_f32_16x16x32_bf16(a, b, c, 0, 0, 0);
}

// ---------------- fp32 -> bf16 convert (batch + 3 weight matrices) ----------
__global__ void cvt_kernel(const float* __restrict__ batch,
                           const float* __restrict__ wq,
                           const float* __restrict__ wk,
                           const float* __restrict__ wv,
                           u16* __restrict__ Xb, u16* __restrict__ Wqb,
                           u16* __restrict__ Wkb, u16* __restrict__ Wvb) {
  const int MD4 = NM * ND / 4;
  const int W4 = ND * ND / 4;
  int total = MD4 + 3 * W4;
  for (int i = blockIdx.x * blockDim.x + threadIdx.x; i < total;
       i += gridDim.x * blockDim.x) {
    const float4* src; u16x4* dst; int off;
    if (i < MD4)             { src = (const float4*)batch; dst = (u16x4*)Xb;  off = i; }
    else if (i < MD4 + W4)   { src = (const float4*)wq;    dst = (u16x4*)Wqb; off = i - MD4; }
    else if (i < MD4 + 2*W4) { src = (const float4*)wk;    dst = (u16x4*)Wkb; off = i - MD4 - W4; }
    else                     { src = (const float4*)wv;    dst = (u16x4*)Wvb; off = i - MD4 - 2*W4; }
    float4 v = src[off];
    u16x4 o; o[0] = f2bf(v.x); o[1] = f2bf(v.y); o[2] = f2bf(v.z); o[3] = f2bf(v.w);
    dst[off] = o;
  }
}

// ---------------- QKV projection GEMM ---------------------------------------
__global__ __launch_bounds__(256) void qkv_gemm(
    const u16* __restrict__ Xb,
    const u16* __restrict__ Wqb, const u16* __restrict__ Wkb, const u16* __restrict__ Wvb,
    const float* __restrict__ bq, const float* __restrict__ bk, const float* __restrict__ bv,
    u16* __restrict__ Qb, u16* __restrict__ Kb, u16* __restrict__ Vt) {
  __shared__ u16 Asm[128 * 64];
  __shared__ u16 Bsm[128 * 64];
  int tid = threadIdx.x;
  int w = tid >> 6, lane = tid & 63, la = lane & 15, hi = lane >> 4;
  int wm = w >> 1, wn = w & 1;
  int m0 = blockIdx.x * 128, n0 = blockIdx.y * 128, z = blockIdx.z;
  const u16* W = (z == 0) ? Wqb : (z == 1) ? Wkb : Wvb;
  f32x4 acc[4][4];
  f32x4 zero = {0.f, 0.f, 0.f, 0.f};
#pragma unroll
  for (int mi = 0; mi < 4; ++mi)
#pragma unroll
    for (int ni = 0; ni < 4; ++ni) acc[mi][ni] = zero;

  for (int kt = 0; kt < 8; ++kt) {
#pragma unroll
    for (int i = 0; i < 4; ++i) {
      int c = w * 4 + i;
      int row = c * 8 + (lane >> 3);
      const char* ga = (const char*)Xb + ((size_t)(m0 + row) * ND + kt * 64) * 2 + (lane & 7) * 16;
      GLD16(ga, (char*)Asm + c * 1024);
      const char* gb = (const char*)W + ((size_t)(n0 + row) * ND + kt * 64) * 2 + (lane & 7) * 16;
      GLD16(gb, (char*)Bsm + c * 1024);
    }
    __syncthreads();
#pragma unroll
    for (int kk = 0; kk < 2; ++kk) {
      bf16x8 a[4], bfr[4];
#pragma unroll
      for (int mi = 0; mi < 4; ++mi)
        a[mi] = *(const bf16x8*)((const char*)Asm + (wm * 64 + mi * 16 + la) * 128 + kk * 64 + hi * 16);
#pragma unroll
      for (int ni = 0; ni < 4; ++ni)
        bfr[ni] = *(const bf16x8*)((const char*)Bsm + (wn * 64 + ni * 16 + la) * 128 + kk * 64 + hi * 16);
#pragma unroll
      for (int mi = 0; mi < 4; ++mi)
#pragma unroll
        for (int ni = 0; ni < 4; ++ni)
          acc[mi][ni] = mfma16(a[mi], bfr[ni], acc[mi][ni]);
    }
    __syncthreads();
  }

  const float* bias = (z == 0) ? bq : (z == 1) ? bk : bv;
  float scl = (z == 0) ? 0.044194173824159216f : 1.0f;  // 1/sqrt(512) folded into Q
#pragma unroll
  for (int mi = 0; mi < 4; ++mi) {
#pragma unroll
    for (int ni = 0; ni < 4; ++ni) {
      int col = n0 + wn * 64 + ni * 16 + la;
      int rbase = m0 + wm * 64 + mi * 16 + hi * 4;
      float bc = bias[col];
      if (z == 2) {
        int bbx = rbase >> 11, s0 = rbase & 2047;
        u16x4 pk;
#pragma unroll
        for (int j = 0; j < 4; ++j) pk[j] = f2bf(acc[mi][ni][j] + bc);
        *(u16x4*)((char*)Vt + (((size_t)bbx * ND + col) * NS + s0) * 2) = pk;
      } else {
        u16* Ob = (z == 0) ? Qb : Kb;
#pragma unroll
        for (int j = 0; j < 4; ++j)
          Ob[(size_t)(rbase + j) * ND + col] = f2bf((acc[mi][ni][j] + bc) * scl);
      }
    }
  }
}

// ---------------- flash attention (split-K, pipelined) ----------------------
// Work item i (512 blocks, long-first): qt = 31-(i>>4); b = (i&15)&7; c = (i&15)>>3.
// Chunk c covers K-tiles [c*16, min(lastT+1, c*16+16)), KVBLK=64.
// 4 waves: QK^T per wave = 16 q-rows (swapped, lane la owns a q-row);
// PV per wave = 64q x 128d slice (V-frags register-cached across 4 q-blocks).
// Counted-vmcnt pipeline: K_{t+1} staged after QK_t, V_{t+1} after PV_t;
// waits are vmcnt(16), never 0 mid-loop; raw s_barrier (no compiler drain).
__global__ __launch_bounds__(256, 1) void attn_kernel(
    const u16* __restrict__ Qb, const u16* __restrict__ Kb, const u16* __restrict__ Vt,
    const int* __restrict__ lens, float* __restrict__ out,
    float* __restrict__ pO, float* __restrict__ pM, float* __restrict__ pL) {
  __shared__ u16 Ksm[64 * 512];    // 64 KB
  __shared__ u16 Vsm[512 * 64];    // 64 KB ([d][k] tile)
  __shared__ u16 Psm[64 * 72];     // 9 KB, row stride 144B
  __shared__ float Alds[64];
  __shared__ float Llds[64];

  int bi = blockIdx.x;
  int qt = 31 - (bi >> 4);
  int jj0 = bi & 15;
  int b = jj0 & 7, c = jj0 >> 3;
  int len = lens[b];
  int q0 = qt * 64;
  int kmax = min(q0 + 63, len - 1);
  int lastT = kmax >> 6;
  int t0 = c * 16;
  int t1 = min(lastT + 1, t0 + 16);
  bool split = (qt >= 16);
  int slot = split ? ((b * 16 + (qt - 16)) * 2 + c) : 0;
  int tid = threadIdx.x;
  int w = tid >> 6, lane = tid & 63, la = lane & 15, hi = lane >> 4;

  if (t0 >= t1) {            // no work in this chunk
    if (split && tid < 64) { pM[slot * 64 + tid] = -1e30f; pL[slot * 64 + tid] = 0.f; }
    return;
  }

  int r0 = q0 + w * 16;
  int qrow = r0 + la;        // q-row this lane owns in S^T domain

  // Q fragments (resident whole kernel)
  bf16x8 qf[16];
  const char* qbase = (const char*)Qb + (size_t)(b * NS + r0 + la) * ND * 2 + hi * 16;
#pragma unroll
  for (int kc = 0; kc < 16; ++kc) qf[kc] = *(const bf16x8*)(qbase + kc * 64);

  f32x4 o[4][8];             // O[q = qb*16+hi*4+j][d = w*128+nb*16+la]
  f32x4 zero = {0.f, 0.f, 0.f, 0.f};
#pragma unroll
  for (int qb = 0; qb < 4; ++qb)
#pragma unroll
    for (int nb = 0; nb < 8; ++nb) o[qb][nb] = zero;
  float mrow = -1e30f, lrow = 0.f;

#define STAGE_K(T) {                                                            \
  _Pragma("unroll")                                                             \
  for (int i_ = 0; i_ < 16; ++i_) {                                             \
    int r_ = w * 16 + i_;                                                       \
    const char* g_ = (const char*)Kb + (size_t)(b * NS + (T) * 64 + r_) * ND * 2 \
                     + ((lane ^ (r_ & 7)) * 16);                                \
    GLD16(g_, (char*)Ksm + r_ * 1024);                                          \
  } }
#define STAGE_V(T) {                                                            \
  _Pragma("unroll")                                                             \
  for (int i_ = 0; i_ < 16; ++i_) {                                             \
    int c_ = w * 16 + i_;                                                       \
    int d_ = c_ * 8 + (lane >> 3);                                              \
    const char* g_ = (const char*)Vt + ((size_t)(b * ND + d_) * NS + (T) * 64) * 2 \
                     + (((lane & 7) ^ (d_ & 7)) * 16);                          \
    GLD16(g_, (char*)Vsm + c_ * 1024);                                          \
  } }

  STAGE_K(t0);
  STAGE_V(t0);

  for (int t = t0; t < t1; ++t) {
    int k0 = t * 64;
    bool more = (t + 1 < t1);
    // wait K_t landed (V_t still outstanding: 16)
    asm volatile("s_waitcnt vmcnt(16)" ::: "memory");
    __builtin_amdgcn_s_barrier();

    // QK^T (swapped): s[f] holds keys f*16+hi*4+j for q-row la
    f32x4 s[4];
#pragma unroll
    for (int f = 0; f < 4; ++f) s[f] = zero;
#pragma unroll
    for (int kc = 0; kc < 16; ++kc) {
#pragma unroll
      for (int f = 0; f < 4; ++f) {
        int row = f * 16 + la;
        const char* p = (const char*)Ksm + row * 1024 + ((kc * 64 + hi * 16) ^ ((row & 7) * 16));
        bf16x8 kf = *(const bf16x8*)p;
        s[f] = mfma16(kf, qf[kc], s[f]);
      }
    }
    __builtin_amdgcn_s_barrier();   // all waves done reading Ksm
    if (more) STAGE_K(t + 1);

    // mask + online softmax (per q-row = lane la, replicated across hi)
    float tmax = -1e30f;
#pragma unroll
    for (int f = 0; f < 4; ++f) {
#pragma unroll
      for (int j = 0; j < 4; ++j) {
        int kabs = k0 + f * 16 + hi * 4 + j;
        bool ok = (kabs <= qrow) && (kabs < len);
        float vv = ok ? s[f][j] : -1e30f;
        s[f][j] = vv;
        tmax = fmaxf(tmax, vv);
      }
    }
    tmax = fmaxf(tmax, __shfl_xor(tmax, 16));
    tmax = fmaxf(tmax, __shfl_xor(tmax, 32));
    // floor: all-masked rows (possible in chunk 1) keep p == 0, l == 0
    float mnew = fmaxf(fmaxf(mrow, tmax), -1e20f);
    float alpha = __expf(mrow - mnew);
    float psum = 0.f;
#pragma unroll
    for (int f = 0; f < 4; ++f) {
#pragma unroll
      for (int j = 0; j < 4; ++j) {
        float p = __expf(s[f][j] - mnew);
        s[f][j] = p;
        psum += p;
      }
    }
    psum += __shfl_xor(psum, 16);
    psum += __shfl_xor(psum, 32);
    lrow = lrow * alpha + psum;
    mrow = mnew;

    // publish P (bf16) + alpha
#pragma unroll
    for (int f = 0; f < 4; ++f) {
      u16x4 pk;
#pragma unroll
      for (int j = 0; j < 4; ++j) pk[j] = f2bf(s[f][j]);
      *(u16x4*)((char*)Psm + (w * 16 + la) * 144 + (f * 16 + hi * 4) * 2) = pk;
    }
    if (hi == 0) Alds[w * 16 + la] = alpha;
    asm volatile("s_waitcnt lgkmcnt(0)" ::: "memory");
    // wait V_t landed (K_{t+1} outstanding if staged)
    if (more) { asm volatile("s_waitcnt vmcnt(16)" ::: "memory"); }
    else      { asm volatile("s_waitcnt vmcnt(0)" ::: "memory"); }
    __builtin_amdgcn_s_barrier();   // P, Alds, Vsm all visible

    // rescale O by alpha (per O-row q = qb*16+hi*4+j)
    float aq[4][4];
#pragma unroll
    for (int qb = 0; qb < 4; ++qb)
#pragma unroll
      for (int j = 0; j < 4; ++j) aq[qb][j] = Alds[qb * 16 + hi * 4 + j];
#pragma unroll
    for (int qb = 0; qb < 4; ++qb)
#pragma unroll
      for (int nb = 0; nb < 8; ++nb) {
        o[qb][nb][0] *= aq[qb][0]; o[qb][nb][1] *= aq[qb][1];
        o[qb][nb][2] *= aq[qb][2]; o[qb][nb][3] *= aq[qb][3];
      }

    // PV: wave owns d-slice w*128..+128; V-frags cached across 4 q-blocks
#pragma unroll
    for (int ks = 0; ks < 2; ++ks) {
      bf16x8 vf[8];
#pragma unroll
      for (int nb = 0; nb < 8; ++nb) {
        int d = w * 128 + nb * 16 + la;
        vf[nb] = *(const bf16x8*)((const char*)Vsm + d * 128 + ((ks * 64 + hi * 16) ^ ((d & 7) * 16)));
      }
#pragma unroll
      for (int qb = 0; qb < 4; ++qb) {
        bf16x8 pf = *(const bf16x8*)((const char*)Psm + (qb * 16 + la) * 144 + ks * 64 + hi * 16);
#pragma unroll
        for (int nb = 0; nb < 8; ++nb) o[qb][nb] = mfma16(pf, vf[nb], o[qb][nb]);
      }
    }
    __builtin_amdgcn_s_barrier();   // done reading Vsm/Psm
    if (more) STAGE_V(t + 1);
  }

  if (split) {
    if (hi == 0) { pM[slot * 64 + w * 16 + la] = mrow; pL[slot * 64 + w * 16 + la] = lrow; }
    float* dst = pO + (size_t)slot * 32768;
#pragma unroll
    for (int qb = 0; qb < 4; ++qb)
#pragma unroll
      for (int nb = 0; nb < 8; ++nb) {
        int d = w * 128 + nb * 16 + la;
#pragma unroll
        for (int j = 0; j < 4; ++j)
          dst[(size_t)(qb * 16 + hi * 4 + j) * ND + d] = o[qb][nb][j];
      }
  } else {
    if (hi == 0) Llds[w * 16 + la] = lrow;
    asm volatile("s_waitcnt lgkmcnt(0)" ::: "memory");
    __builtin_amdgcn_s_barrier();
    float li[4][4];
#pragma unroll
    for (int qb = 0; qb < 4; ++qb)
#pragma unroll
      for (int j = 0; j < 4; ++j) li[qb][j] = 1.0f / Llds[qb * 16 + hi * 4 + j];
    float* dst = out + ((size_t)b * NS + q0) * ND;
#pragma unroll
    for (int qb = 0; qb < 4; ++qb)
#pragma unroll
      for (int nb = 0; nb < 8; ++nb) {
        int d = w * 128 + nb * 16 + la;
#pragma unroll
        for (int j = 0; j < 4; ++j)
          dst[(size_t)(qb * 16 + hi * 4 + j) * ND + d] = o[qb][nb][j] * li[qb][j];
      }
  }
#undef STAGE_K
#undef STAGE_V
}

// ---------------- combine split-K partials ----------------------------------
__global__ __launch_bounds__(256) void combine_kernel(
    const float* __restrict__ pO, const float* __restrict__ pM,
    const float* __restrict__ pL, float* __restrict__ out) {
  int qt = 16 + blockIdx.x, b = blockIdx.y;
  int s0 = (b * 16 + (qt - 16)) * 2;
  int tid = threadIdx.x;
  int row = tid >> 2, dp = tid & 3;
  float m0 = pM[s0 * 64 + row], m1 = pM[(s0 + 1) * 64 + row];
  float l0 = pL[s0 * 64 + row], l1 = pL[(s0 + 1) * 64 + row];
  float m = fmaxf(m0, m1);
  float a0 = __expf(m0 - m), a1 = __expf(m1 - m);
  float linv = 1.0f / (l0 * a0 + l1 * a1);
  const float4* O0 = (const float4*)(pO + (size_t)s0 * 32768) + row * 128 + dp * 32;
  const float4* O1 = (const float4*)(pO + (size_t)(s0 + 1) * 32768) + row * 128 + dp * 32;
  float4* Op = (float4*)(out + ((size_t)b * NS + qt * 64 + row) * ND) + dp * 32;
  bool has1 = (l1 > 0.f);
  float c0 = a0 * linv, c1 = a1 * linv;
#pragma unroll 8
  for (int k = 0; k < 32; ++k) {
    float4 v = O0[k], r;
    if (has1) {
      float4 v1 = O1[k];
      r.x = v.x * c0 + v1.x * c1; r.y = v.y * c0 + v1.y * c1;
      r.z = v.z * c0 + v1.z * c1; r.w = v.w * c0 + v1.w * c1;
    } else {
      r.x = v.x * c0; r.y = v.y * c0; r.z = v.z * c0; r.w = v.w * c0;
    }
    Op[k] = r;
  }
}

extern "C" void kernel_launch(void* const* d_in, const int* in_sizes, int n_in,
                              void* d_out, int out_size, void* d_ws, size_t ws_size,
                              hipStream_t stream) {
  const float* batch = (const float*)d_in[0];
  const float* wq = (const float*)d_in[1];
  const float* bq = (const float*)d_in[2];
  const float* wk = (const float*)d_in[3];
  const float* bk = (const float*)d_in[4];
  const float* wv = (const float*)d_in[5];
  const float* bv = (const float*)d_in[6];
  const int* lens = (const int*)d_in[7];

  char* ws = (char*)d_ws;
  u16* Xb  = (u16*)(ws + 0);          // 16 MB
  u16* Wqb = (u16*)(ws + 16777216);   // 512 KB
  u16* Wkb = (u16*)(ws + 17301504);   // 512 KB
  u16* Wvb = (u16*)(ws + 17825792);   // 512 KB
  u16* Qb  = (u16*)(ws + 18350080);   // 16 MB
  u16* Kb  = (u16*)(ws + 35127296);   // 16 MB
  u16* Vt  = (u16*)(ws + 51904512);   // 16 MB
  float* pO = (float*)(ws + 68681728);   // 33.55 MB (256 slots x 64x512 f32)
  float* pM = (float*)(ws + 102236160);  // 64 KB
  float* pL = (float*)(ws + 102301696);  // 64 KB  (total ws use: 102367232 B)

  cvt_kernel<<<dim3(2048), dim3(256), 0, stream>>>(batch, wq, wk, wv, Xb, Wqb, Wkb, Wvb);
  qkv_gemm<<<dim3(128, 4, 3), dim3(256), 0, stream>>>(Xb, Wqb, Wkb, Wvb, bq, bk, bv, Qb, Kb, Vt);
  attn_kernel<<<dim3(512), dim3(256), 0, stream>>>(Qb, Kb, Vt, lens, (float*)d_out, pO, pM, pL);
  combine_kernel<<<dim3(16, 8), dim3(256), 0, stream>>>(pO, pM, pL, (float*)d_out);
}